// Round 4
// baseline (57.909 us; speedup 1.0000x reference)
//
#include <hip/hip_runtime.h>
#include <hip/hip_fp16.h>

#define NIMG 2
#define CCH 256
#define FH 128
#define FW 128
#define FHW (FH * FW)
#define OUTH 7
#define OUTW 7
#define NPIX 49
#define KROIS 1024
#define SCALE 0.0625f
#define OPITCH 260  // halves; 520 B row pitch, 8B-aligned

typedef float f32x4 __attribute__((ext_vector_type(4)));

// ---------------- ROI spatial sort: key = (batch, morton(center)) ----------------
// 1 block, 1024 threads, bitonic in LDS. Deterministic (keys made unique with idx).
__global__ __launch_bounds__(1024) void sort_rois(const float* __restrict__ rois,
                                                  int* __restrict__ perm) {
    __shared__ unsigned long long keys[KROIS];
    const int t = threadIdx.x;
    const float* r = rois + t * 5;
    const int b = (int)r[0];
    const float cx = (r[1] + r[3]) * 0.5f * SCALE;
    const float cy = (r[2] + r[4]) * 0.5f * SCALE;
    const int qx = (int)fminf(fmaxf(cx, 0.f), 127.f);
    const int qy = (int)fminf(fmaxf(cy, 0.f), 127.f);
    unsigned m = 0;
#pragma unroll
    for (int i = 0; i < 7; ++i)
        m |= (((unsigned)(qx >> i) & 1u) << (2 * i)) | (((unsigned)(qy >> i) & 1u) << (2 * i + 1));
    const unsigned key = ((unsigned)b << 14) | m;
    keys[t] = ((unsigned long long)key << 32) | (unsigned)t;
    __syncthreads();
    for (int ksz = 2; ksz <= KROIS; ksz <<= 1) {
        for (int j = ksz >> 1; j > 0; j >>= 1) {
            const int ixj = t ^ j;
            if (ixj > t) {
                const unsigned long long a = keys[t];
                const unsigned long long c = keys[ixj];
                if ((a > c) == ((t & ksz) == 0)) { keys[t] = c; keys[ixj] = a; }
            }
            __syncthreads();
        }
    }
    perm[t] = (int)(keys[t] & 0xffffffffu);
}

// ---------------- NCHW f32 -> NHWC fp16 transpose+convert ----------------
__global__ __launch_bounds__(256) void nchw_to_nhwc_h(const float* __restrict__ in,
                                                      __half* __restrict__ out) {
    __shared__ float tile[32][33];
    const int b   = blockIdx.z;
    const int hw0 = blockIdx.x << 5;
    const int c0  = blockIdx.y << 5;
    const int tx  = threadIdx.x;
    const int ty  = threadIdx.y;
    const float* src = in  + (size_t)b * CCH * FHW;
    __half*      dst = out + (size_t)b * FHW * CCH;
#pragma unroll
    for (int i = 0; i < 32; i += 8)
        tile[ty + i][tx] = src[(size_t)(c0 + ty + i) * FHW + hw0 + tx];
    __syncthreads();
#pragma unroll
    for (int i = 0; i < 32; i += 8)
        dst[(size_t)(hw0 + ty + i) * CCH + c0 + tx] = __float2half(tile[tx][ty + i]);
}

// ---------------- main RoIAlign on NHWC fp16 ----------------
__global__ __launch_bounds__(512) void roi_align_nhwc(const __half* __restrict__ nhwc,
                                                      const float* __restrict__ rois,
                                                      const int* __restrict__ perm,
                                                      float* __restrict__ out) {
    __shared__ __half obuf[NPIX * OPITCH];  // 25,480 B -> 4 blocks/CU (wave-capped)
    const int wg = blockIdx.x;
    // XCD-chunked swizzle over spatially-sorted ROIs: each XCD gets 128 adjacent ROIs
    const int k = perm[((wg & 7) << 7) | (wg >> 3)];
    const int lane = threadIdx.x & 63;
    const int wave = threadIdx.x >> 6;

    const float* r = rois + k * 5;
    const int b = (int)r[0];
    const float x1 = __fsub_rn(__fmul_rn(r[1], SCALE), 0.5f);
    const float y1 = __fsub_rn(__fmul_rn(r[2], SCALE), 0.5f);
    const float x2 = __fsub_rn(__fmul_rn(r[3], SCALE), 0.5f);
    const float y2 = __fsub_rn(__fmul_rn(r[4], SCALE), 0.5f);
    const float bw = __fdiv_rn(__fsub_rn(x2, x1), (float)OUTW);
    const float bh = __fdiv_rn(__fsub_rn(y2, y1), (float)OUTH);
    const __half* fb = nhwc + ((size_t)b * FHW << 8) + (lane << 2);  // lane owns 4 channels

    for (int pix = wave; pix < NPIX; pix += 8) {
        const int ph = pix / 7;
        const int pw = pix - ph * 7;
        float acc0 = 0.f, acc1 = 0.f, acc2 = 0.f, acc3 = 0.f;
#pragma unroll
        for (int s = 0; s < 4; ++s) {
            const int sy = s >> 1, sx = s & 1;
            const float fy = (float)ph + (sy ? 0.75f : 0.25f);  // exact in f32
            const float fx = (float)pw + (sx ? 0.75f : 0.25f);  // exact in f32
            const float y = __fadd_rn(y1, __fmul_rn(fy, bh));   // match numpy rounding
            const float x = __fadd_rn(x1, __fmul_rn(fx, bw));
            if (y > -1.0f && y < (float)FH && x > -1.0f && x < (float)FW) {
                const float yc = fmaxf(y, 0.0f);
                const float xc = fmaxf(x, 0.0f);
                int y0 = (int)yc; if (y0 > FH - 1) y0 = FH - 1;
                int x0 = (int)xc; if (x0 > FW - 1) x0 = FW - 1;
                const int y1i = min(y0 + 1, FH - 1);
                const int x1i = min(x0 + 1, FW - 1);
                const float ly = fminf(yc - (float)y0, 1.0f);
                const float lx = fminf(xc - (float)x0, 1.0f);
                const float hy = 1.0f - ly, hx = 1.0f - lx;
                const float w00 = hy * hx, w01 = hy * lx, w10 = ly * hx, w11 = ly * lx;
                const __half2* q00 = (const __half2*)(fb + ((size_t)(y0  * FW + x0 ) << 8));
                const __half2* q01 = (const __half2*)(fb + ((size_t)(y0  * FW + x1i) << 8));
                const __half2* q10 = (const __half2*)(fb + ((size_t)(y1i * FW + x0 ) << 8));
                const __half2* q11 = (const __half2*)(fb + ((size_t)(y1i * FW + x1i) << 8));
                const __half2 A00 = q00[0], B00 = q00[1];
                const __half2 A01 = q01[0], B01 = q01[1];
                const __half2 A10 = q10[0], B10 = q10[1];
                const __half2 A11 = q11[0], B11 = q11[1];
                // fma_mix-friendly form: f16->f32 convert fused into the FMA (exact)
                acc0 = fmaf(w00, __half2float(A00.x), acc0);
                acc1 = fmaf(w00, __half2float(A00.y), acc1);
                acc2 = fmaf(w00, __half2float(B00.x), acc2);
                acc3 = fmaf(w00, __half2float(B00.y), acc3);
                acc0 = fmaf(w01, __half2float(A01.x), acc0);
                acc1 = fmaf(w01, __half2float(A01.y), acc1);
                acc2 = fmaf(w01, __half2float(B01.x), acc2);
                acc3 = fmaf(w01, __half2float(B01.y), acc3);
                acc0 = fmaf(w10, __half2float(A10.x), acc0);
                acc1 = fmaf(w10, __half2float(A10.y), acc1);
                acc2 = fmaf(w10, __half2float(B10.x), acc2);
                acc3 = fmaf(w10, __half2float(B10.y), acc3);
                acc0 = fmaf(w11, __half2float(A11.x), acc0);
                acc1 = fmaf(w11, __half2float(A11.y), acc1);
                acc2 = fmaf(w11, __half2float(B11.x), acc2);
                acc3 = fmaf(w11, __half2float(B11.y), acc3);
            }
        }
        const __half2 h01 = __floats2half2_rn(acc0 * 0.25f, acc1 * 0.25f);
        const __half2 h23 = __floats2half2_rn(acc2 * 0.25f, acc3 * 0.25f);
        uint2 packed;
        packed.x = *(const unsigned*)&h01;
        packed.y = *(const unsigned*)&h23;
        *(uint2*)&obuf[pix * OPITCH + (lane << 2)] = packed;
    }
    __syncthreads();

    // coalesced writeout: out[k][c][pix], 12544 contiguous floats, non-temporal
    float* op = out + (size_t)k * (CCH * NPIX);
    for (int f4 = threadIdx.x; f4 < (CCH * NPIX) / 4; f4 += 512) {
        const int f = f4 << 2;
        f32x4 o;
        {
            const int fi = f + 0; const int c = fi / NPIX; const int p = fi - c * NPIX;
            o.x = __half2float(obuf[p * OPITCH + c]);
        }
        {
            const int fi = f + 1; const int c = fi / NPIX; const int p = fi - c * NPIX;
            o.y = __half2float(obuf[p * OPITCH + c]);
        }
        {
            const int fi = f + 2; const int c = fi / NPIX; const int p = fi - c * NPIX;
            o.z = __half2float(obuf[p * OPITCH + c]);
        }
        {
            const int fi = f + 3; const int c = fi / NPIX; const int p = fi - c * NPIX;
            o.w = __half2float(obuf[p * OPITCH + c]);
        }
        __builtin_nontemporal_store(o, (f32x4*)(op + f));
    }
}

// ---------------- fallback: direct NCHW f32, one thread per output element ----------------
__global__ __launch_bounds__(256) void roi_align_naive(const float* __restrict__ feat,
                                                       const float* __restrict__ rois,
                                                       float* __restrict__ out) {
    const size_t idx = (size_t)blockIdx.x * 256 + threadIdx.x;
    const size_t total = (size_t)KROIS * CCH * NPIX;
    if (idx >= total) return;
    const int pix = (int)(idx % NPIX);
    const int t1  = (int)(idx / NPIX);
    const int c   = t1 % CCH;
    const int k   = t1 / CCH;
    const int ph = pix / 7;
    const int pw = pix - ph * 7;

    const float* r = rois + k * 5;
    const int b = (int)r[0];
    const float x1 = __fsub_rn(__fmul_rn(r[1], SCALE), 0.5f);
    const float y1 = __fsub_rn(__fmul_rn(r[2], SCALE), 0.5f);
    const float x2 = __fsub_rn(__fmul_rn(r[3], SCALE), 0.5f);
    const float y2 = __fsub_rn(__fmul_rn(r[4], SCALE), 0.5f);
    const float bw = __fdiv_rn(__fsub_rn(x2, x1), (float)OUTW);
    const float bh = __fdiv_rn(__fsub_rn(y2, y1), (float)OUTH);
    const float* fp = feat + (size_t)(b * CCH + c) * FHW;

    float acc = 0.f;
#pragma unroll
    for (int s = 0; s < 4; ++s) {
        const int sy = s >> 1, sx = s & 1;
        const float fy = (float)ph + (sy ? 0.75f : 0.25f);
        const float fx = (float)pw + (sx ? 0.75f : 0.25f);
        const float y = __fadd_rn(y1, __fmul_rn(fy, bh));
        const float x = __fadd_rn(x1, __fmul_rn(fx, bw));
        if (y > -1.0f && y < (float)FH && x > -1.0f && x < (float)FW) {
            const float yc = fmaxf(y, 0.0f);
            const float xc = fmaxf(x, 0.0f);
            int y0 = (int)yc; if (y0 > FH - 1) y0 = FH - 1;
            int x0 = (int)xc; if (x0 > FW - 1) x0 = FW - 1;
            const int y1i = min(y0 + 1, FH - 1);
            const int x1i = min(x0 + 1, FW - 1);
            const float ly = fminf(yc - (float)y0, 1.0f);
            const float lx = fminf(xc - (float)x0, 1.0f);
            const float hy = 1.0f - ly, hx = 1.0f - lx;
            acc += (hy * hx) * fp[y0  * FW + x0 ] + (hy * lx) * fp[y0  * FW + x1i]
                 + (ly * hx) * fp[y1i * FW + x0 ] + (ly * lx) * fp[y1i * FW + x1i];
        }
    }
    out[idx] = acc * 0.25f;
}

extern "C" void kernel_launch(void* const* d_in, const int* in_sizes, int n_in,
                              void* d_out, int out_size, void* d_ws, size_t ws_size,
                              hipStream_t stream) {
    const float* feat = (const float*)d_in[0];
    const float* rois = (const float*)d_in[1];
    float* out = (float*)d_out;

    const size_t nhwc_bytes = (size_t)NIMG * CCH * FHW * sizeof(__half);  // 16.8 MB
    const size_t need = nhwc_bytes + KROIS * sizeof(int);
    if (ws_size >= need) {
        __half* nhwc = (__half*)d_ws;
        int* perm = (int*)((char*)d_ws + nhwc_bytes);
        sort_rois<<<dim3(1), dim3(KROIS), 0, stream>>>(rois, perm);
        dim3 tg(FHW / 32, CCH / 32, NIMG);
        nchw_to_nhwc_h<<<tg, dim3(32, 8), 0, stream>>>(feat, nhwc);
        roi_align_nhwc<<<dim3(KROIS), dim3(512), 0, stream>>>(nhwc, rois, perm, out);
    } else {
        const size_t total = (size_t)KROIS * CCH * NPIX;
        roi_align_naive<<<dim3((unsigned)((total + 255) / 256)), dim3(256), 0, stream>>>(feat, rois, out);
    }
}

// Round 5
// 48.751 us; speedup vs baseline: 1.1879x; 1.1879x over previous
//
#include <hip/hip_runtime.h>
#include <hip/hip_fp16.h>

#define NIMG 2
#define CCH 256
#define FH 128
#define FW 128
#define FHW (FH * FW)
#define OUTH 7
#define OUTW 7
#define NPIX 49
#define NSAMP (NPIX * 4)
#define KROIS 1024
#define SCALE 0.0625f
#define OPITCH 260  // halves; 520 B row pitch

typedef float f32x4 __attribute__((ext_vector_type(4)));

// ---------------- ROI locality grouping: LDS counting sort, 128 buckets ----------------
// bucket = (batch << 6) | morton6(center/16px). Within-bucket order is scheduling-
// dependent, but output is bit-identical for any permutation (each ROI's math and
// output slot are fixed); only L2 locality depends on it.
__global__ __launch_bounds__(1024) void sort_rois(const float* __restrict__ rois,
                                                  int* __restrict__ perm) {
    __shared__ int hist[128];
    __shared__ int basep[128];
    const int t = threadIdx.x;
    if (t < 128) hist[t] = 0;
    __syncthreads();
    const float* r = rois + t * 5;
    const int b = (int)r[0];
    const float cx = (r[1] + r[3]) * 0.5f * SCALE;
    const float cy = (r[2] + r[4]) * 0.5f * SCALE;
    const int qx = min(max((int)cx, 0), FW - 1) >> 4;  // 0..7
    const int qy = min(max((int)cy, 0), FH - 1) >> 4;  // 0..7
    unsigned m = 0;
#pragma unroll
    for (int i = 0; i < 3; ++i)
        m |= (((unsigned)(qx >> i) & 1u) << (2 * i)) | (((unsigned)(qy >> i) & 1u) << (2 * i + 1));
    const int key = (b << 6) | (int)m;
    const int rank = atomicAdd(&hist[key], 1);
    __syncthreads();
    if (t < 64) {  // one-wave exclusive scan of 128 bins (2 bins/lane)
        const int a = hist[2 * t], c = hist[2 * t + 1];
        int s = a + c;
#pragma unroll
        for (int d = 1; d < 64; d <<= 1) {
            const int n = __shfl_up(s, d);
            if (t >= d) s += n;
        }
        const int excl = s - (a + c);
        basep[2 * t]     = excl;
        basep[2 * t + 1] = excl + a;
    }
    __syncthreads();
    perm[basep[key] + rank] = t;
}

// ---------------- NCHW f32 -> NHWC fp16 transpose+convert ----------------
__global__ __launch_bounds__(256) void nchw_to_nhwc_h(const float* __restrict__ in,
                                                      __half* __restrict__ out) {
    __shared__ float tile[32][33];
    const int b   = blockIdx.z;
    const int hw0 = blockIdx.x << 5;
    const int c0  = blockIdx.y << 5;
    const int tx  = threadIdx.x;
    const int ty  = threadIdx.y;
    const float* src = in  + (size_t)b * CCH * FHW;
    __half*      dst = out + (size_t)b * FHW * CCH;
#pragma unroll
    for (int i = 0; i < 32; i += 8)
        tile[ty + i][tx] = src[(size_t)(c0 + ty + i) * FHW + hw0 + tx];
    __syncthreads();
#pragma unroll
    for (int i = 0; i < 32; i += 8)
        dst[(size_t)(hw0 + ty + i) * CCH + c0 + tx] = __float2half(tile[tx][ty + i]);
}

// ---------------- main RoIAlign on NHWC fp16 ----------------
__global__ __launch_bounds__(512) void roi_align_nhwc(const __half* __restrict__ nhwc,
                                                      const float* __restrict__ rois,
                                                      const int* __restrict__ perm,
                                                      float* __restrict__ out) {
    __shared__ __half obuf[NPIX * OPITCH];                 // 25,480 B
    __shared__ __align__(16) int   soff[NSAMP][4];         // 3,136 B
    __shared__ __align__(16) float swgt[NSAMP][4];         // 3,136 B
    const int wg = blockIdx.x;
    // XCD-chunked swizzle over bucket-sorted ROIs: XCD x gets sorted chunk [x*128, x*128+128)
    const int k = perm[((wg & 7) << 7) | (wg >> 3)];
    const int lane = threadIdx.x & 63;
    const int wave = threadIdx.x >> 6;
    const int t = threadIdx.x;

    const float* r = rois + k * 5;
    const int b = __builtin_amdgcn_readfirstlane((int)r[0]);

    // phase 0: one thread per (pix,sample) computes offsets+weights once (exact R3 math)
    if (t < NSAMP) {
        const float x1 = __fsub_rn(__fmul_rn(r[1], SCALE), 0.5f);
        const float y1 = __fsub_rn(__fmul_rn(r[2], SCALE), 0.5f);
        const float x2 = __fsub_rn(__fmul_rn(r[3], SCALE), 0.5f);
        const float y2 = __fsub_rn(__fmul_rn(r[4], SCALE), 0.5f);
        const float bw = __fdiv_rn(__fsub_rn(x2, x1), (float)OUTW);
        const float bh = __fdiv_rn(__fsub_rn(y2, y1), (float)OUTH);
        const int pix = t >> 2, s = t & 3;
        const int ph = pix / 7, pw = pix - ph * 7;
        const int sy = s >> 1, sx = s & 1;
        const float fy = (float)ph + (sy ? 0.75f : 0.25f);
        const float fx = (float)pw + (sx ? 0.75f : 0.25f);
        const float y = __fadd_rn(y1, __fmul_rn(fy, bh));
        const float x = __fadd_rn(x1, __fmul_rn(fx, bw));
        int o00 = 0, o01 = 0, o10 = 0, o11 = 0;
        float w00 = 0.f, w01 = 0.f, w10 = 0.f, w11 = 0.f;
        if (y > -1.0f && y < (float)FH && x > -1.0f && x < (float)FW) {
            const float yc = fmaxf(y, 0.0f);
            const float xc = fmaxf(x, 0.0f);
            int y0 = (int)yc; if (y0 > FH - 1) y0 = FH - 1;
            int x0 = (int)xc; if (x0 > FW - 1) x0 = FW - 1;
            const int y1i = min(y0 + 1, FH - 1);
            const int x1i = min(x0 + 1, FW - 1);
            const float ly = fminf(yc - (float)y0, 1.0f);
            const float lx = fminf(xc - (float)x0, 1.0f);
            const float hy = 1.0f - ly, hx = 1.0f - lx;
            w00 = hy * hx; w01 = hy * lx; w10 = ly * hx; w11 = ly * lx;
            o00 = (y0  * FW + x0 ) << 9;  // *512 B (256 fp16 channels)
            o01 = (y0  * FW + x1i) << 9;
            o10 = (y1i * FW + x0 ) << 9;
            o11 = (y1i * FW + x1i) << 9;
        }
        soff[t][0] = o00; soff[t][1] = o01; soff[t][2] = o10; soff[t][3] = o11;
        swgt[t][0] = w00; swgt[t][1] = w01; swgt[t][2] = w10; swgt[t][3] = w11;
    }
    __syncthreads();

    // phase 2: pure gather + fma_mix; addresses = SGPR base + 32-bit voffset
    const char* bp = (const char*)(nhwc + ((size_t)b * FHW << 8)) + (lane << 3);
    for (int pix = wave; pix < NPIX; pix += 8) {
        float acc0 = 0.f, acc1 = 0.f, acc2 = 0.f, acc3 = 0.f;
#pragma unroll
        for (int s = 0; s < 4; ++s) {
            const int j = (pix << 2) + s;
            const int4  o = *(const int4*)(&soff[j][0]);
            const f32x4 w = *(const f32x4*)(&swgt[j][0]);
            const uint2 r00 = *(const uint2*)(bp + o.x);
            const uint2 r01 = *(const uint2*)(bp + o.y);
            const uint2 r10 = *(const uint2*)(bp + o.z);
            const uint2 r11 = *(const uint2*)(bp + o.w);
            const __half2 A00 = *(const __half2*)&r00.x, B00 = *(const __half2*)&r00.y;
            const __half2 A01 = *(const __half2*)&r01.x, B01 = *(const __half2*)&r01.y;
            const __half2 A10 = *(const __half2*)&r10.x, B10 = *(const __half2*)&r10.y;
            const __half2 A11 = *(const __half2*)&r11.x, B11 = *(const __half2*)&r11.y;
            acc0 = fmaf(w.x, __half2float(A00.x), acc0);
            acc1 = fmaf(w.x, __half2float(A00.y), acc1);
            acc2 = fmaf(w.x, __half2float(B00.x), acc2);
            acc3 = fmaf(w.x, __half2float(B00.y), acc3);
            acc0 = fmaf(w.y, __half2float(A01.x), acc0);
            acc1 = fmaf(w.y, __half2float(A01.y), acc1);
            acc2 = fmaf(w.y, __half2float(B01.x), acc2);
            acc3 = fmaf(w.y, __half2float(B01.y), acc3);
            acc0 = fmaf(w.z, __half2float(A10.x), acc0);
            acc1 = fmaf(w.z, __half2float(A10.y), acc1);
            acc2 = fmaf(w.z, __half2float(B10.x), acc2);
            acc3 = fmaf(w.z, __half2float(B10.y), acc3);
            acc0 = fmaf(w.w, __half2float(A11.x), acc0);
            acc1 = fmaf(w.w, __half2float(A11.y), acc1);
            acc2 = fmaf(w.w, __half2float(B11.x), acc2);
            acc3 = fmaf(w.w, __half2float(B11.y), acc3);
        }
        const __half2 h01 = __floats2half2_rn(acc0 * 0.25f, acc1 * 0.25f);
        const __half2 h23 = __floats2half2_rn(acc2 * 0.25f, acc3 * 0.25f);
        uint2 packed;
        packed.x = *(const unsigned*)&h01;
        packed.y = *(const unsigned*)&h23;
        *(uint2*)&obuf[pix * OPITCH + (lane << 2)] = packed;
    }
    __syncthreads();

    // coalesced writeout: out[k][c][pix], non-temporal (don't evict fp16 map from L2)
    float* op = out + (size_t)k * (CCH * NPIX);
    for (int f4 = threadIdx.x; f4 < (CCH * NPIX) / 4; f4 += 512) {
        const int f = f4 << 2;
        f32x4 o;
        {
            const int fi = f + 0; const int c = fi / NPIX; const int p = fi - c * NPIX;
            o.x = __half2float(obuf[p * OPITCH + c]);
        }
        {
            const int fi = f + 1; const int c = fi / NPIX; const int p = fi - c * NPIX;
            o.y = __half2float(obuf[p * OPITCH + c]);
        }
        {
            const int fi = f + 2; const int c = fi / NPIX; const int p = fi - c * NPIX;
            o.z = __half2float(obuf[p * OPITCH + c]);
        }
        {
            const int fi = f + 3; const int c = fi / NPIX; const int p = fi - c * NPIX;
            o.w = __half2float(obuf[p * OPITCH + c]);
        }
        __builtin_nontemporal_store(o, (f32x4*)(op + f));
    }
}

// ---------------- fallback: direct NCHW f32, one thread per output element ----------------
__global__ __launch_bounds__(256) void roi_align_naive(const float* __restrict__ feat,
                                                       const float* __restrict__ rois,
                                                       float* __restrict__ out) {
    const size_t idx = (size_t)blockIdx.x * 256 + threadIdx.x;
    const size_t total = (size_t)KROIS * CCH * NPIX;
    if (idx >= total) return;
    const int pix = (int)(idx % NPIX);
    const int t1  = (int)(idx / NPIX);
    const int c   = t1 % CCH;
    const int k   = t1 / CCH;
    const int ph = pix / 7;
    const int pw = pix - ph * 7;

    const float* r = rois + k * 5;
    const int b = (int)r[0];
    const float x1 = __fsub_rn(__fmul_rn(r[1], SCALE), 0.5f);
    const float y1 = __fsub_rn(__fmul_rn(r[2], SCALE), 0.5f);
    const float x2 = __fsub_rn(__fmul_rn(r[3], SCALE), 0.5f);
    const float y2 = __fsub_rn(__fmul_rn(r[4], SCALE), 0.5f);
    const float bw = __fdiv_rn(__fsub_rn(x2, x1), (float)OUTW);
    const float bh = __fdiv_rn(__fsub_rn(y2, y1), (float)OUTH);
    const float* fp = feat + (size_t)(b * CCH + c) * FHW;

    float acc = 0.f;
#pragma unroll
    for (int s = 0; s < 4; ++s) {
        const int sy = s >> 1, sx = s & 1;
        const float fy = (float)ph + (sy ? 0.75f : 0.25f);
        const float fx = (float)pw + (sx ? 0.75f : 0.25f);
        const float y = __fadd_rn(y1, __fmul_rn(fy, bh));
        const float x = __fadd_rn(x1, __fmul_rn(fx, bw));
        if (y > -1.0f && y < (float)FH && x > -1.0f && x < (float)FW) {
            const float yc = fmaxf(y, 0.0f);
            const float xc = fmaxf(x, 0.0f);
            int y0 = (int)yc; if (y0 > FH - 1) y0 = FH - 1;
            int x0 = (int)xc; if (x0 > FW - 1) x0 = FW - 1;
            const int y1i = min(y0 + 1, FH - 1);
            const int x1i = min(x0 + 1, FW - 1);
            const float ly = fminf(yc - (float)y0, 1.0f);
            const float lx = fminf(xc - (float)x0, 1.0f);
            const float hy = 1.0f - ly, hx = 1.0f - lx;
            acc += (hy * hx) * fp[y0  * FW + x0 ] + (hy * lx) * fp[y0  * FW + x1i]
                 + (ly * hx) * fp[y1i * FW + x0 ] + (ly * lx) * fp[y1i * FW + x1i];
        }
    }
    out[idx] = acc * 0.25f;
}

extern "C" void kernel_launch(void* const* d_in, const int* in_sizes, int n_in,
                              void* d_out, int out_size, void* d_ws, size_t ws_size,
                              hipStream_t stream) {
    const float* feat = (const float*)d_in[0];
    const float* rois = (const float*)d_in[1];
    float* out = (float*)d_out;

    const size_t nhwc_bytes = (size_t)NIMG * CCH * FHW * sizeof(__half);  // 16.8 MB
    const size_t need = nhwc_bytes + KROIS * sizeof(int);
    if (ws_size >= need) {
        __half* nhwc = (__half*)d_ws;
        int* perm = (int*)((char*)d_ws + nhwc_bytes);
        sort_rois<<<dim3(1), dim3(KROIS), 0, stream>>>(rois, perm);
        dim3 tg(FHW / 32, CCH / 32, NIMG);
        nchw_to_nhwc_h<<<tg, dim3(32, 8), 0, stream>>>(feat, nhwc);
        roi_align_nhwc<<<dim3(KROIS), dim3(512), 0, stream>>>(nhwc, rois, perm, out);
    } else {
        const size_t total = (size_t)KROIS * CCH * NPIX;
        roi_align_naive<<<dim3((unsigned)((total + 255) / 256)), dim3(256), 0, stream>>>(feat, rois, out);
    }
}

// Round 6
// 48.599 us; speedup vs baseline: 1.1916x; 1.0031x over previous
//
#include <hip/hip_runtime.h>
#include <hip/hip_fp16.h>

#define NIMG 2
#define CCH 256
#define FH 128
#define FW 128
#define FHW (FH * FW)
#define OUTH 7
#define OUTW 7
#define NPIX 49
#define NSAMP (NPIX * 4)
#define KROIS 1024
#define SCALE 0.0625f
#define OPITCH 260  // halves; 520 B row pitch

typedef float f32x4 __attribute__((ext_vector_type(4)));

// ---------------- fused: NCHW->NHWC fp16 transpose (blocks 0..8191) + ROI bucket sort (block 8192) ----------------
// sort: bucket = (batch<<6) | morton6(center/16px); LDS counting sort. Within-bucket
// order is scheduling-dependent but output is bit-identical for any ROI->block map.
__global__ __launch_bounds__(256) void prep_fused(const float* __restrict__ in,
                                                  __half* __restrict__ out,
                                                  const float* __restrict__ rois,
                                                  int* __restrict__ perm) {
    const int bid = blockIdx.x;
    const int t = threadIdx.x;
    if (bid < 8192) {
        __shared__ float tile[32][33];
        const int b   = bid >> 12;
        const int rem = bid & 4095;
        const int c0  = (rem >> 9) << 5;
        const int hw0 = (rem & 511) << 5;
        const int tx = t & 31;
        const int ty = t >> 5;
        const float* src = in  + (size_t)b * CCH * FHW;
        __half*      dst = out + (size_t)b * FHW * CCH;
#pragma unroll
        for (int i = 0; i < 32; i += 8)
            tile[ty + i][tx] = src[(size_t)(c0 + ty + i) * FHW + hw0 + tx];
        __syncthreads();
#pragma unroll
        for (int i = 0; i < 32; i += 8)
            dst[(size_t)(hw0 + ty + i) * CCH + c0 + tx] = __float2half(tile[tx][ty + i]);
    } else {
        __shared__ int hist[128];
        __shared__ int basep[128];
        __shared__ int keyv[KROIS];
        __shared__ int rankv[KROIS];
        if (t < 128) hist[t] = 0;
        __syncthreads();
#pragma unroll
        for (int i = 0; i < 4; ++i) {
            const int roi = t + (i << 8);
            const float* r = rois + roi * 5;
            const int b = (int)r[0];
            const float cx = (r[1] + r[3]) * 0.5f * SCALE;
            const float cy = (r[2] + r[4]) * 0.5f * SCALE;
            const int qx = min(max((int)cx, 0), FW - 1) >> 4;  // 0..7
            const int qy = min(max((int)cy, 0), FH - 1) >> 4;  // 0..7
            unsigned m = 0;
#pragma unroll
            for (int j = 0; j < 3; ++j)
                m |= (((unsigned)(qx >> j) & 1u) << (2 * j)) | (((unsigned)(qy >> j) & 1u) << (2 * j + 1));
            const int key = (b << 6) | (int)m;
            keyv[roi] = key;
            rankv[roi] = atomicAdd(&hist[key], 1);
        }
        __syncthreads();
        if (t < 64) {  // one-wave exclusive scan over 128 bins (2/lane)
            const int a = hist[2 * t], c = hist[2 * t + 1];
            int s = a + c;
#pragma unroll
            for (int d = 1; d < 64; d <<= 1) {
                const int n = __shfl_up(s, d);
                if (t >= d) s += n;
            }
            const int excl = s - (a + c);
            basep[2 * t]     = excl;
            basep[2 * t + 1] = excl + a;
        }
        __syncthreads();
#pragma unroll
        for (int i = 0; i < 4; ++i) {
            const int roi = t + (i << 8);
            perm[basep[keyv[roi]] + rankv[roi]] = roi;
        }
    }
}

// ---------------- main RoIAlign on NHWC fp16: 512 blocks x 2 sorted-adjacent ROIs ----------------
__global__ __launch_bounds__(512) void roi_align_nhwc(const __half* __restrict__ nhwc,
                                                      const float* __restrict__ rois,
                                                      const int* __restrict__ perm,
                                                      float* __restrict__ out) {
    __shared__ __half obuf[NPIX * OPITCH];                 // 25,480 B
    __shared__ __align__(16) int   soff[NSAMP][4];         // 3,136 B
    __shared__ __align__(16) float swgt[NSAMP][4];         // 3,136 B
    const int wg = blockIdx.x;
    // XCD-chunked: XCD x runs sorted pair-chunk [x*64, x*64+64) -> 128 adjacent ROIs,
    // ~64 live at once (2 blocks/CU, sequential pair) -> working set fits 4MB L2.
    const int pairBase = ((((wg & 7) << 6) | (wg >> 3)) << 1);
    const int lane = threadIdx.x & 63;
    const int wave = threadIdx.x >> 6;
    const int t = threadIdx.x;

    for (int half = 0; half < 2; ++half) {
        const int k = perm[pairBase + half];
        const float* r = rois + k * 5;
        const int b = __builtin_amdgcn_readfirstlane((int)r[0]);

        // phase 0: one thread per (pix,sample) computes offsets+weights (exact ref math)
        if (t < NSAMP) {
            const float x1 = __fsub_rn(__fmul_rn(r[1], SCALE), 0.5f);
            const float y1 = __fsub_rn(__fmul_rn(r[2], SCALE), 0.5f);
            const float x2 = __fsub_rn(__fmul_rn(r[3], SCALE), 0.5f);
            const float y2 = __fsub_rn(__fmul_rn(r[4], SCALE), 0.5f);
            const float bw = __fdiv_rn(__fsub_rn(x2, x1), (float)OUTW);
            const float bh = __fdiv_rn(__fsub_rn(y2, y1), (float)OUTH);
            const int pix = t >> 2, s = t & 3;
            const int ph = pix / 7, pw = pix - ph * 7;
            const int sy = s >> 1, sx = s & 1;
            const float fy = (float)ph + (sy ? 0.75f : 0.25f);
            const float fx = (float)pw + (sx ? 0.75f : 0.25f);
            const float y = __fadd_rn(y1, __fmul_rn(fy, bh));
            const float x = __fadd_rn(x1, __fmul_rn(fx, bw));
            int o00 = 0, o01 = 0, o10 = 0, o11 = 0;
            float w00 = 0.f, w01 = 0.f, w10 = 0.f, w11 = 0.f;
            if (y > -1.0f && y < (float)FH && x > -1.0f && x < (float)FW) {
                const float yc = fmaxf(y, 0.0f);
                const float xc = fmaxf(x, 0.0f);
                int y0 = (int)yc; if (y0 > FH - 1) y0 = FH - 1;
                int x0 = (int)xc; if (x0 > FW - 1) x0 = FW - 1;
                const int y1i = min(y0 + 1, FH - 1);
                const int x1i = min(x0 + 1, FW - 1);
                const float ly = fminf(yc - (float)y0, 1.0f);
                const float lx = fminf(xc - (float)x0, 1.0f);
                const float hy = 1.0f - ly, hx = 1.0f - lx;
                w00 = hy * hx; w01 = hy * lx; w10 = ly * hx; w11 = ly * lx;
                o00 = (y0  * FW + x0 ) << 9;  // *512 B (256 fp16 channels)
                o01 = (y0  * FW + x1i) << 9;
                o10 = (y1i * FW + x0 ) << 9;
                o11 = (y1i * FW + x1i) << 9;
            }
            soff[t][0] = o00; soff[t][1] = o01; soff[t][2] = o10; soff[t][3] = o11;
            swgt[t][0] = w00; swgt[t][1] = w01; swgt[t][2] = w10; swgt[t][3] = w11;
        }
        __syncthreads();

        // phase 1: gather + fma_mix. Contiguous pix per wave -> corner-row reuse in L1/L2.
        const char* bp = (const char*)(nhwc + ((size_t)b * FHW << 8)) + (lane << 3);
        const int pstart = wave ? (6 * wave + 1) : 0;
        const int pend   = 6 * wave + 6;  // inclusive
        for (int pix = pstart; pix <= pend; ++pix) {
            float acc0 = 0.f, acc1 = 0.f, acc2 = 0.f, acc3 = 0.f;
#pragma unroll
            for (int s = 0; s < 4; ++s) {
                const int j = (pix << 2) + s;
                const int4  o = *(const int4*)(&soff[j][0]);
                const f32x4 w = *(const f32x4*)(&swgt[j][0]);
                const uint2 r00 = *(const uint2*)(bp + o.x);
                const uint2 r01 = *(const uint2*)(bp + o.y);
                const uint2 r10 = *(const uint2*)(bp + o.z);
                const uint2 r11 = *(const uint2*)(bp + o.w);
                const __half2 A00 = *(const __half2*)&r00.x, B00 = *(const __half2*)&r00.y;
                const __half2 A01 = *(const __half2*)&r01.x, B01 = *(const __half2*)&r01.y;
                const __half2 A10 = *(const __half2*)&r10.x, B10 = *(const __half2*)&r10.y;
                const __half2 A11 = *(const __half2*)&r11.x, B11 = *(const __half2*)&r11.y;
                acc0 = fmaf(w.x, __half2float(A00.x), acc0);
                acc1 = fmaf(w.x, __half2float(A00.y), acc1);
                acc2 = fmaf(w.x, __half2float(B00.x), acc2);
                acc3 = fmaf(w.x, __half2float(B00.y), acc3);
                acc0 = fmaf(w.y, __half2float(A01.x), acc0);
                acc1 = fmaf(w.y, __half2float(A01.y), acc1);
                acc2 = fmaf(w.y, __half2float(B01.x), acc2);
                acc3 = fmaf(w.y, __half2float(B01.y), acc3);
                acc0 = fmaf(w.z, __half2float(A10.x), acc0);
                acc1 = fmaf(w.z, __half2float(A10.y), acc1);
                acc2 = fmaf(w.z, __half2float(B10.x), acc2);
                acc3 = fmaf(w.z, __half2float(B10.y), acc3);
                acc0 = fmaf(w.w, __half2float(A11.x), acc0);
                acc1 = fmaf(w.w, __half2float(A11.y), acc1);
                acc2 = fmaf(w.w, __half2float(B11.x), acc2);
                acc3 = fmaf(w.w, __half2float(B11.y), acc3);
            }
            const __half2 h01 = __floats2half2_rn(acc0 * 0.25f, acc1 * 0.25f);
            const __half2 h23 = __floats2half2_rn(acc2 * 0.25f, acc3 * 0.25f);
            uint2 packed;
            packed.x = *(const unsigned*)&h01;
            packed.y = *(const unsigned*)&h23;
            *(uint2*)&obuf[pix * OPITCH + (lane << 2)] = packed;
        }
        __syncthreads();

        // phase 2: coalesced writeout out[k][c][pix], non-temporal
        float* op = out + (size_t)k * (CCH * NPIX);
        for (int f4 = t; f4 < (CCH * NPIX) / 4; f4 += 512) {
            const int f = f4 << 2;
            f32x4 o;
            {
                const int fi = f + 0; const int c = fi / NPIX; const int p = fi - c * NPIX;
                o.x = __half2float(obuf[p * OPITCH + c]);
            }
            {
                const int fi = f + 1; const int c = fi / NPIX; const int p = fi - c * NPIX;
                o.y = __half2float(obuf[p * OPITCH + c]);
            }
            {
                const int fi = f + 2; const int c = fi / NPIX; const int p = fi - c * NPIX;
                o.z = __half2float(obuf[p * OPITCH + c]);
            }
            {
                const int fi = f + 3; const int c = fi / NPIX; const int p = fi - c * NPIX;
                o.w = __half2float(obuf[p * OPITCH + c]);
            }
            __builtin_nontemporal_store(o, (f32x4*)(op + f));
        }
        __syncthreads();  // protect obuf/soff/swgt before next half overwrites
    }
}

// ---------------- fallback: direct NCHW f32, one thread per output element ----------------
__global__ __launch_bounds__(256) void roi_align_naive(const float* __restrict__ feat,
                                                       const float* __restrict__ rois,
                                                       float* __restrict__ out) {
    const size_t idx = (size_t)blockIdx.x * 256 + threadIdx.x;
    const size_t total = (size_t)KROIS * CCH * NPIX;
    if (idx >= total) return;
    const int pix = (int)(idx % NPIX);
    const int t1  = (int)(idx / NPIX);
    const int c   = t1 % CCH;
    const int k   = t1 / CCH;
    const int ph = pix / 7;
    const int pw = pix - ph * 7;

    const float* r = rois + k * 5;
    const int b = (int)r[0];
    const float x1 = __fsub_rn(__fmul_rn(r[1], SCALE), 0.5f);
    const float y1 = __fsub_rn(__fmul_rn(r[2], SCALE), 0.5f);
    const float x2 = __fsub_rn(__fmul_rn(r[3], SCALE), 0.5f);
    const float y2 = __fsub_rn(__fmul_rn(r[4], SCALE), 0.5f);
    const float bw = __fdiv_rn(__fsub_rn(x2, x1), (float)OUTW);
    const float bh = __fdiv_rn(__fsub_rn(y2, y1), (float)OUTH);
    const float* fp = feat + (size_t)(b * CCH + c) * FHW;

    float acc = 0.f;
#pragma unroll
    for (int s = 0; s < 4; ++s) {
        const int sy = s >> 1, sx = s & 1;
        const float fy = (float)ph + (sy ? 0.75f : 0.25f);
        const float fx = (float)pw + (sx ? 0.75f : 0.25f);
        const float y = __fadd_rn(y1, __fmul_rn(fy, bh));
        const float x = __fadd_rn(x1, __fmul_rn(fx, bw));
        if (y > -1.0f && y < (float)FH && x > -1.0f && x < (float)FW) {
            const float yc = fmaxf(y, 0.0f);
            const float xc = fmaxf(x, 0.0f);
            int y0 = (int)yc; if (y0 > FH - 1) y0 = FH - 1;
            int x0 = (int)xc; if (x0 > FW - 1) x0 = FW - 1;
            const int y1i = min(y0 + 1, FH - 1);
            const int x1i = min(x0 + 1, FW - 1);
            const float ly = fminf(yc - (float)y0, 1.0f);
            const float lx = fminf(xc - (float)x0, 1.0f);
            const float hy = 1.0f - ly, hx = 1.0f - lx;
            acc += (hy * hx) * fp[y0  * FW + x0 ] + (hy * lx) * fp[y0  * FW + x1i]
                 + (ly * hx) * fp[y1i * FW + x0 ] + (ly * lx) * fp[y1i * FW + x1i];
        }
    }
    out[idx] = acc * 0.25f;
}

extern "C" void kernel_launch(void* const* d_in, const int* in_sizes, int n_in,
                              void* d_out, int out_size, void* d_ws, size_t ws_size,
                              hipStream_t stream) {
    const float* feat = (const float*)d_in[0];
    const float* rois = (const float*)d_in[1];
    float* out = (float*)d_out;

    const size_t nhwc_bytes = (size_t)NIMG * CCH * FHW * sizeof(__half);  // 16.8 MB
    const size_t need = nhwc_bytes + KROIS * sizeof(int);
    if (ws_size >= need) {
        __half* nhwc = (__half*)d_ws;
        int* perm = (int*)((char*)d_ws + nhwc_bytes);
        prep_fused<<<dim3(8193), dim3(256), 0, stream>>>(feat, nhwc, rois, perm);
        roi_align_nhwc<<<dim3(512), dim3(512), 0, stream>>>(nhwc, rois, perm, out);
    } else {
        const size_t total = (size_t)KROIS * CCH * NPIX;
        roi_align_naive<<<dim3((unsigned)((total + 255) / 256)), dim3(256), 0, stream>>>(feat, rois, out);
    }
}

// Round 7
// 46.166 us; speedup vs baseline: 1.2544x; 1.0527x over previous
//
#include <hip/hip_runtime.h>
#include <hip/hip_fp16.h>

#define NIMG 2
#define CCH 256
#define HALFC 128
#define FH 128
#define FW 128
#define FHW (FH * FW)
#define OUTH 7
#define OUTW 7
#define NPIX 49
#define NSAMP (NPIX * 4)
#define KROIS 1024
#define SCALE 0.0625f
#define OPITCH 132   // halves; 264 B row pitch
#define MAXJ 384     // block slots per XCD; j-loop handles overflow correctly

typedef float f32x4 __attribute__((ext_vector_type(4)));

// ---------------- fused: NCHW->NHWC fp16 transpose (blocks 0..8191) + ROI group sort (block 8192) ----
// sort key = (group<<5) | cell, group = (batch<<1)|rowhalf (of ROI center), cell = 16px grid.
// Output is bit-identical for any within-bucket order; only L2 locality depends on it.
__global__ __launch_bounds__(256) void prep_fused(const float* __restrict__ in,
                                                  __half* __restrict__ out,
                                                  const float* __restrict__ rois,
                                                  int* __restrict__ perm,
                                                  int* __restrict__ bases) {
    const int bid = blockIdx.x;
    const int t = threadIdx.x;
    if (bid < 8192) {
        __shared__ float tile[32][33];
        const int b   = bid >> 12;
        const int rem = bid & 4095;
        const int c0  = (rem >> 9) << 5;
        const int hw0 = (rem & 511) << 5;
        const int tx = t & 31;
        const int ty = t >> 5;
        const float* src = in  + (size_t)b * CCH * FHW;
        __half*      dst = out + (size_t)b * FHW * CCH;
#pragma unroll
        for (int i = 0; i < 32; i += 8)
            tile[ty + i][tx] = src[(size_t)(c0 + ty + i) * FHW + hw0 + tx];
        __syncthreads();
#pragma unroll
        for (int i = 0; i < 32; i += 8)
            dst[(size_t)(hw0 + ty + i) * CCH + c0 + tx] = __float2half(tile[tx][ty + i]);
    } else {
        __shared__ int hist[128];
        __shared__ int basep[128];
        __shared__ int keyv[KROIS];
        __shared__ int rankv[KROIS];
        if (t < 128) hist[t] = 0;
        __syncthreads();
#pragma unroll
        for (int i = 0; i < 4; ++i) {
            const int roi = t + (i << 8);
            const float* r = rois + roi * 5;
            const int b = (int)r[0];
            const float cx = (r[1] + r[3]) * 0.5f * SCALE;
            const float cy = (r[2] + r[4]) * 0.5f * SCALE;
            const int qcx = min(max((int)cx, 0), FW - 1);
            const int qcy = min(max((int)cy, 0), FH - 1);
            const int g = (b << 1) | (qcy >> 6);                       // image, row-half
            const int cell = (((qcy & 63) >> 4) << 3) | (qcx >> 4);    // 4x8 16px cells
            const int key = (g << 5) | cell;
            keyv[roi] = key;
            rankv[roi] = atomicAdd(&hist[key], 1);
        }
        __syncthreads();
        if (t < 64) {  // one-wave exclusive scan over 128 bins (2/lane)
            const int a = hist[2 * t], c = hist[2 * t + 1];
            int s = a + c;
#pragma unroll
            for (int d = 1; d < 64; d <<= 1) {
                const int n = __shfl_up(s, d);
                if (t >= d) s += n;
            }
            const int excl = s - (a + c);
            basep[2 * t]     = excl;
            basep[2 * t + 1] = excl + a;
        }
        __syncthreads();
        if (t < 4) bases[t] = basep[t << 5];  // group starts
        if (t == 0) bases[4] = KROIS;
#pragma unroll
        for (int i = 0; i < 4; ++i) {
            const int roi = t + (i << 8);
            perm[basep[keyv[roi]] + rankv[roi]] = roi;
        }
    }
}

// ---------------- main RoIAlign: 8-way XCD partition = (channel-plane, image, row-half) ----------------
// XCD x (=bid&7): plane p=x>>2 (128 of 256 channels), group g=x&3. Partition footprint
// = 64rows x 128cols x 128ch x 2B = 2.1MB <= 4MB L2 -> gather becomes L2-resident.
__global__ __launch_bounds__(256, 8) void roi_align_nhwc(const __half* __restrict__ nhwc,
                                                         const float* __restrict__ rois,
                                                         const int* __restrict__ perm,
                                                         const int* __restrict__ bases,
                                                         float* __restrict__ out) {
    __shared__ __half obuf[NPIX * OPITCH];                 // 12,936 B
    __shared__ __align__(16) int   soff[NSAMP][4];         // 3,136 B
    __shared__ __align__(16) float swgt[NSAMP][4];         // 3,136 B
    const int bid = blockIdx.x;
    const int xcd = bid & 7;
    const int p = xcd >> 2;
    const int g = xcd & 3;
    const int base  = bases[g];
    const int count = bases[g + 1] - base;
    const int t = threadIdx.x;
    const int lane = t & 63;
    const int wave = t >> 6;
    const int pstart = wave ? (12 * wave + 1) : 0;          // 0,13,25,37
    const int pend   = pstart + (wave ? 12 : 13);           // exclusive

    for (int j = bid >> 3; j < count; j += MAXJ) {
        const int k = perm[base + j];
        const float* r = rois + k * 5;
        const int b = __builtin_amdgcn_readfirstlane((int)r[0]);

        // phase 0: one thread per (pix,sample) computes offsets+weights (exact ref math)
        if (t < NSAMP) {
            const float x1 = __fsub_rn(__fmul_rn(r[1], SCALE), 0.5f);
            const float y1 = __fsub_rn(__fmul_rn(r[2], SCALE), 0.5f);
            const float x2 = __fsub_rn(__fmul_rn(r[3], SCALE), 0.5f);
            const float y2 = __fsub_rn(__fmul_rn(r[4], SCALE), 0.5f);
            const float bw = __fdiv_rn(__fsub_rn(x2, x1), (float)OUTW);
            const float bh = __fdiv_rn(__fsub_rn(y2, y1), (float)OUTH);
            const int pix = t >> 2, s = t & 3;
            const int ph = pix / 7, pw = pix - ph * 7;
            const int sy = s >> 1, sx = s & 1;
            const float fy = (float)ph + (sy ? 0.75f : 0.25f);
            const float fx = (float)pw + (sx ? 0.75f : 0.25f);
            const float y = __fadd_rn(y1, __fmul_rn(fy, bh));
            const float x = __fadd_rn(x1, __fmul_rn(fx, bw));
            int o00 = 0, o01 = 0, o10 = 0, o11 = 0;
            float w00 = 0.f, w01 = 0.f, w10 = 0.f, w11 = 0.f;
            if (y > -1.0f && y < (float)FH && x > -1.0f && x < (float)FW) {
                const float yc = fmaxf(y, 0.0f);
                const float xc = fmaxf(x, 0.0f);
                int y0 = (int)yc; if (y0 > FH - 1) y0 = FH - 1;
                int x0 = (int)xc; if (x0 > FW - 1) x0 = FW - 1;
                const int y1i = min(y0 + 1, FH - 1);
                const int x1i = min(x0 + 1, FW - 1);
                const float ly = fminf(yc - (float)y0, 1.0f);
                const float lx = fminf(xc - (float)x0, 1.0f);
                const float hy = 1.0f - ly, hx = 1.0f - lx;
                w00 = hy * hx; w01 = hy * lx; w10 = ly * hx; w11 = ly * lx;
                o00 = (y0  * FW + x0 ) << 9;  // *512 B (256 fp16 channels per position)
                o01 = (y0  * FW + x1i) << 9;
                o10 = (y1i * FW + x0 ) << 9;
                o11 = (y1i * FW + x1i) << 9;
            }
            soff[t][0] = o00; soff[t][1] = o01; soff[t][2] = o10; soff[t][3] = o11;
            swgt[t][0] = w00; swgt[t][1] = w01; swgt[t][2] = w10; swgt[t][3] = w11;
        }
        __syncthreads();

        // phase 1: gather this plane's 128 channels (2 ch/lane, dword loads) + fma_mix
        const char* bp = (const char*)(nhwc + ((size_t)b * FHW << 8)) + (p << 8) + (lane << 2);
        for (int pix = pstart; pix < pend; ++pix) {
            float acc0 = 0.f, acc1 = 0.f;
#pragma unroll
            for (int s = 0; s < 4; ++s) {
                const int jj = (pix << 2) + s;
                const int4  o = *(const int4*)(&soff[jj][0]);
                const f32x4 w = *(const f32x4*)(&swgt[jj][0]);
                const unsigned r00 = *(const unsigned*)(bp + o.x);
                const unsigned r01 = *(const unsigned*)(bp + o.y);
                const unsigned r10 = *(const unsigned*)(bp + o.z);
                const unsigned r11 = *(const unsigned*)(bp + o.w);
                const __half2 A00 = *(const __half2*)&r00;
                const __half2 A01 = *(const __half2*)&r01;
                const __half2 A10 = *(const __half2*)&r10;
                const __half2 A11 = *(const __half2*)&r11;
                acc0 = fmaf(w.x, __half2float(A00.x), acc0);
                acc1 = fmaf(w.x, __half2float(A00.y), acc1);
                acc0 = fmaf(w.y, __half2float(A01.x), acc0);
                acc1 = fmaf(w.y, __half2float(A01.y), acc1);
                acc0 = fmaf(w.z, __half2float(A10.x), acc0);
                acc1 = fmaf(w.z, __half2float(A10.y), acc1);
                acc0 = fmaf(w.w, __half2float(A11.x), acc0);
                acc1 = fmaf(w.w, __half2float(A11.y), acc1);
            }
            const __half2 h = __floats2half2_rn(acc0 * 0.25f, acc1 * 0.25f);
            *(unsigned*)&obuf[pix * OPITCH + (lane << 1)] = *(const unsigned*)&h;
        }
        __syncthreads();

        // phase 2: coalesced writeout out[k][p*128 + c][pix], non-temporal
        float* op = out + (size_t)k * (CCH * NPIX) + (size_t)p * (HALFC * NPIX);
        for (int f4 = t; f4 < (HALFC * NPIX) / 4; f4 += 256) {
            const int f = f4 << 2;
            f32x4 o;
            {
                const int fi = f + 0; const int c = fi / NPIX; const int pp = fi - c * NPIX;
                o.x = __half2float(obuf[pp * OPITCH + c]);
            }
            {
                const int fi = f + 1; const int c = fi / NPIX; const int pp = fi - c * NPIX;
                o.y = __half2float(obuf[pp * OPITCH + c]);
            }
            {
                const int fi = f + 2; const int c = fi / NPIX; const int pp = fi - c * NPIX;
                o.z = __half2float(obuf[pp * OPITCH + c]);
            }
            {
                const int fi = f + 3; const int c = fi / NPIX; const int pp = fi - c * NPIX;
                o.w = __half2float(obuf[pp * OPITCH + c]);
            }
            __builtin_nontemporal_store(o, (f32x4*)(op + f));
        }
        __syncthreads();  // protect obuf/soff/swgt before next j overwrites
    }
}

// ---------------- fallback: direct NCHW f32, one thread per output element ----------------
__global__ __launch_bounds__(256) void roi_align_naive(const float* __restrict__ feat,
                                                       const float* __restrict__ rois,
                                                       float* __restrict__ out) {
    const size_t idx = (size_t)blockIdx.x * 256 + threadIdx.x;
    const size_t total = (size_t)KROIS * CCH * NPIX;
    if (idx >= total) return;
    const int pix = (int)(idx % NPIX);
    const int t1  = (int)(idx / NPIX);
    const int c   = t1 % CCH;
    const int k   = t1 / CCH;
    const int ph = pix / 7;
    const int pw = pix - ph * 7;

    const float* r = rois + k * 5;
    const int b = (int)r[0];
    const float x1 = __fsub_rn(__fmul_rn(r[1], SCALE), 0.5f);
    const float y1 = __fsub_rn(__fmul_rn(r[2], SCALE), 0.5f);
    const float x2 = __fsub_rn(__fmul_rn(r[3], SCALE), 0.5f);
    const float y2 = __fsub_rn(__fmul_rn(r[4], SCALE), 0.5f);
    const float bw = __fdiv_rn(__fsub_rn(x2, x1), (float)OUTW);
    const float bh = __fdiv_rn(__fsub_rn(y2, y1), (float)OUTH);
    const float* fp = feat + (size_t)(b * CCH + c) * FHW;

    float acc = 0.f;
#pragma unroll
    for (int s = 0; s < 4; ++s) {
        const int sy = s >> 1, sx = s & 1;
        const float fy = (float)ph + (sy ? 0.75f : 0.25f);
        const float fx = (float)pw + (sx ? 0.75f : 0.25f);
        const float y = __fadd_rn(y1, __fmul_rn(fy, bh));
        const float x = __fadd_rn(x1, __fmul_rn(fx, bw));
        if (y > -1.0f && y < (float)FH && x > -1.0f && x < (float)FW) {
            const float yc = fmaxf(y, 0.0f);
            const float xc = fmaxf(x, 0.0f);
            int y0 = (int)yc; if (y0 > FH - 1) y0 = FH - 1;
            int x0 = (int)xc; if (x0 > FW - 1) x0 = FW - 1;
            const int y1i = min(y0 + 1, FH - 1);
            const int x1i = min(x0 + 1, FW - 1);
            const float ly = fminf(yc - (float)y0, 1.0f);
            const float lx = fminf(xc - (float)x0, 1.0f);
            const float hy = 1.0f - ly, hx = 1.0f - lx;
            acc += (hy * hx) * fp[y0  * FW + x0 ] + (hy * lx) * fp[y0  * FW + x1i]
                 + (ly * hx) * fp[y1i * FW + x0 ] + (ly * lx) * fp[y1i * FW + x1i];
        }
    }
    out[idx] = acc * 0.25f;
}

extern "C" void kernel_launch(void* const* d_in, const int* in_sizes, int n_in,
                              void* d_out, int out_size, void* d_ws, size_t ws_size,
                              hipStream_t stream) {
    const float* feat = (const float*)d_in[0];
    const float* rois = (const float*)d_in[1];
    float* out = (float*)d_out;

    const size_t nhwc_bytes = (size_t)NIMG * CCH * FHW * sizeof(__half);  // 16.8 MB
    const size_t need = nhwc_bytes + KROIS * sizeof(int) + 32;
    if (ws_size >= need) {
        __half* nhwc = (__half*)d_ws;
        int* perm = (int*)((char*)d_ws + nhwc_bytes);
        int* bases = perm + KROIS;
        prep_fused<<<dim3(8193), dim3(256), 0, stream>>>(feat, nhwc, rois, perm, bases);
        roi_align_nhwc<<<dim3(8 * MAXJ), dim3(256), 0, stream>>>(nhwc, rois, perm, bases, out);
    } else {
        const size_t total = (size_t)KROIS * CCH * NPIX;
        roi_align_naive<<<dim3((unsigned)((total + 255) / 256)), dim3(256), 0, stream>>>(feat, rois, out);
    }
}

// Round 8
// 43.564 us; speedup vs baseline: 1.3293x; 1.0597x over previous
//
#include <hip/hip_runtime.h>
#include <hip/hip_fp16.h>

#define NIMG 2
#define CCH 256
#define HALFC 128
#define FH 128
#define FW 128
#define FHW (FH * FW)
#define OUTH 7
#define OUTW 7
#define NPIX 49
#define NSAMP (NPIX * 4)
#define KROIS 1024
#define SCALE 0.0625f
#define OPITCH 132   // halves; 264 B row pitch
#define MAXJ 384     // block slots per XCD; j-loop handles overflow correctly

typedef float f32x4 __attribute__((ext_vector_type(4)));

// ---------------- fused: NCHW->NHWC fp16 transpose (blocks 0..8191) + ROI group sort (block 8192) ----
__global__ __launch_bounds__(256) void prep_fused(const float* __restrict__ in,
                                                  __half* __restrict__ out,
                                                  const float* __restrict__ rois,
                                                  int* __restrict__ perm,
                                                  int* __restrict__ bases) {
    const int bid = blockIdx.x;
    const int t = threadIdx.x;
    if (bid < 8192) {
        __shared__ float tile[32][33];
        const int b   = bid >> 12;
        const int rem = bid & 4095;
        const int c0  = (rem >> 9) << 5;
        const int hw0 = (rem & 511) << 5;
        const int tx = t & 31;
        const int ty = t >> 5;
        const float* src = in  + (size_t)b * CCH * FHW;
        __half*      dst = out + (size_t)b * FHW * CCH;
#pragma unroll
        for (int i = 0; i < 32; i += 8)
            tile[ty + i][tx] = src[(size_t)(c0 + ty + i) * FHW + hw0 + tx];
        __syncthreads();
#pragma unroll
        for (int i = 0; i < 32; i += 8)
            dst[(size_t)(hw0 + ty + i) * CCH + c0 + tx] = __float2half(tile[tx][ty + i]);
    } else {
        __shared__ int hist[128];
        __shared__ int basep[128];
        __shared__ int keyv[KROIS];
        __shared__ int rankv[KROIS];
        if (t < 128) hist[t] = 0;
        __syncthreads();
#pragma unroll
        for (int i = 0; i < 4; ++i) {
            const int roi = t + (i << 8);
            const float* r = rois + roi * 5;
            const int b = (int)r[0];
            const float cx = (r[1] + r[3]) * 0.5f * SCALE;
            const float cy = (r[2] + r[4]) * 0.5f * SCALE;
            const int qcx = min(max((int)cx, 0), FW - 1);
            const int qcy = min(max((int)cy, 0), FH - 1);
            const int g = (b << 1) | (qcy >> 6);                       // image, row-half
            const int cell = (((qcy & 63) >> 4) << 3) | (qcx >> 4);    // 4x8 16px cells
            const int key = (g << 5) | cell;
            keyv[roi] = key;
            rankv[roi] = atomicAdd(&hist[key], 1);
        }
        __syncthreads();
        if (t < 64) {  // one-wave exclusive scan over 128 bins (2/lane)
            const int a = hist[2 * t], c = hist[2 * t + 1];
            int s = a + c;
#pragma unroll
            for (int d = 1; d < 64; d <<= 1) {
                const int n = __shfl_up(s, d);
                if (t >= d) s += n;
            }
            const int excl = s - (a + c);
            basep[2 * t]     = excl;
            basep[2 * t + 1] = excl + a;
        }
        __syncthreads();
        if (t < 4) bases[t] = basep[t << 5];  // group starts
        if (t == 0) bases[4] = KROIS;
#pragma unroll
        for (int i = 0; i < 4; ++i) {
            const int roi = t + (i << 8);
            perm[basep[keyv[roi]] + rankv[roi]] = roi;
        }
    }
}

// ---------------- main RoIAlign: 8-way XCD partition = (channel-plane, image, row-half) ----------------
// launch_bounds(256,4): <=128 VGPR so the 16 gather loads per pixel can sit in
// registers simultaneously (MLP), instead of the 64-VGPR load->wait->use chain.
__global__ __launch_bounds__(256, 4) void roi_align_nhwc(const __half* __restrict__ nhwc,
                                                         const float* __restrict__ rois,
                                                         const int* __restrict__ perm,
                                                         const int* __restrict__ bases,
                                                         float* __restrict__ out) {
    __shared__ __half obuf[NPIX * OPITCH];                 // 12,936 B
    __shared__ __align__(16) int   soff[NSAMP][4];         // 3,136 B
    __shared__ __align__(16) float swgt[NSAMP][4];         // 3,136 B
    const int bid = blockIdx.x;
    const int xcd = bid & 7;
    const int p = xcd >> 2;
    const int g = xcd & 3;
    const int base  = bases[g];
    const int count = bases[g + 1] - base;
    const int t = threadIdx.x;
    const int lane = t & 63;
    const int wave = t >> 6;
    const int pstart = wave ? (12 * wave + 1) : 0;          // 0,13,25,37
    const int pcnt   = wave ? 12 : 13;

    for (int j = bid >> 3; j < count; j += MAXJ) {
        const int k = perm[base + j];
        const float* r = rois + k * 5;
        const int b = __builtin_amdgcn_readfirstlane((int)r[0]);

        // phase 0: one thread per (pix,sample) computes offsets+weights (exact ref math)
        if (t < NSAMP) {
            const float x1 = __fsub_rn(__fmul_rn(r[1], SCALE), 0.5f);
            const float y1 = __fsub_rn(__fmul_rn(r[2], SCALE), 0.5f);
            const float x2 = __fsub_rn(__fmul_rn(r[3], SCALE), 0.5f);
            const float y2 = __fsub_rn(__fmul_rn(r[4], SCALE), 0.5f);
            const float bw = __fdiv_rn(__fsub_rn(x2, x1), (float)OUTW);
            const float bh = __fdiv_rn(__fsub_rn(y2, y1), (float)OUTH);
            const int pix = t >> 2, s = t & 3;
            const int ph = pix / 7, pw = pix - ph * 7;
            const int sy = s >> 1, sx = s & 1;
            const float fy = (float)ph + (sy ? 0.75f : 0.25f);
            const float fx = (float)pw + (sx ? 0.75f : 0.25f);
            const float y = __fadd_rn(y1, __fmul_rn(fy, bh));
            const float x = __fadd_rn(x1, __fmul_rn(fx, bw));
            int o00 = 0, o01 = 0, o10 = 0, o11 = 0;
            float w00 = 0.f, w01 = 0.f, w10 = 0.f, w11 = 0.f;
            if (y > -1.0f && y < (float)FH && x > -1.0f && x < (float)FW) {
                const float yc = fmaxf(y, 0.0f);
                const float xc = fmaxf(x, 0.0f);
                int y0 = (int)yc; if (y0 > FH - 1) y0 = FH - 1;
                int x0 = (int)xc; if (x0 > FW - 1) x0 = FW - 1;
                const int y1i = min(y0 + 1, FH - 1);
                const int x1i = min(x0 + 1, FW - 1);
                const float ly = fminf(yc - (float)y0, 1.0f);
                const float lx = fminf(xc - (float)x0, 1.0f);
                const float hy = 1.0f - ly, hx = 1.0f - lx;
                w00 = hy * hx; w01 = hy * lx; w10 = ly * hx; w11 = ly * lx;
                o00 = (y0  * FW + x0 ) << 9;  // *512 B (256 fp16 channels per position)
                o01 = (y0  * FW + x1i) << 9;
                o10 = (y1i * FW + x0 ) << 9;
                o11 = (y1i * FW + x1i) << 9;
            }
            soff[t][0] = o00; soff[t][1] = o01; soff[t][2] = o10; soff[t][3] = o11;
            swgt[t][0] = w00; swgt[t][1] = w01; swgt[t][2] = w10; swgt[t][3] = w11;
        }
        __syncthreads();

        // phase 1: gather this plane's 128 channels (2 ch/lane). Fully unrolled;
        // all 16 corner dwords of a pixel loaded into regs BEFORE the fma batch.
        const char* bp = (const char*)(nhwc + ((size_t)b * FHW << 8)) + (p << 8) + (lane << 2);
#pragma unroll
        for (int i = 0; i < 13; ++i) {
            if (i < pcnt) {
                const int pix = pstart + i;
                unsigned rv[16];
#pragma unroll
                for (int s = 0; s < 4; ++s) {
                    const int4 o = *(const int4*)(&soff[(pix << 2) + s][0]);
                    rv[4 * s + 0] = *(const unsigned*)(bp + o.x);
                    rv[4 * s + 1] = *(const unsigned*)(bp + o.y);
                    rv[4 * s + 2] = *(const unsigned*)(bp + o.z);
                    rv[4 * s + 3] = *(const unsigned*)(bp + o.w);
                }
                float acc0 = 0.f, acc1 = 0.f;
#pragma unroll
                for (int s = 0; s < 4; ++s) {
                    const f32x4 w = *(const f32x4*)(&swgt[(pix << 2) + s][0]);
                    const __half2 A0 = *(const __half2*)&rv[4 * s + 0];
                    const __half2 A1 = *(const __half2*)&rv[4 * s + 1];
                    const __half2 A2 = *(const __half2*)&rv[4 * s + 2];
                    const __half2 A3 = *(const __half2*)&rv[4 * s + 3];
                    acc0 = fmaf(w.x, __half2float(A0.x), acc0);
                    acc1 = fmaf(w.x, __half2float(A0.y), acc1);
                    acc0 = fmaf(w.y, __half2float(A1.x), acc0);
                    acc1 = fmaf(w.y, __half2float(A1.y), acc1);
                    acc0 = fmaf(w.z, __half2float(A2.x), acc0);
                    acc1 = fmaf(w.z, __half2float(A2.y), acc1);
                    acc0 = fmaf(w.w, __half2float(A3.x), acc0);
                    acc1 = fmaf(w.w, __half2float(A3.y), acc1);
                }
                const __half2 h = __floats2half2_rn(acc0 * 0.25f, acc1 * 0.25f);
                *(unsigned*)&obuf[pix * OPITCH + (lane << 1)] = *(const unsigned*)&h;
            }
        }
        __syncthreads();

        // phase 2: coalesced writeout out[k][p*128 + c][pix], non-temporal
        float* op = out + (size_t)k * (CCH * NPIX) + (size_t)p * (HALFC * NPIX);
        for (int f4 = t; f4 < (HALFC * NPIX) / 4; f4 += 256) {
            const int f = f4 << 2;
            f32x4 o;
            {
                const int fi = f + 0; const int c = fi / NPIX; const int pp = fi - c * NPIX;
                o.x = __half2float(obuf[pp * OPITCH + c]);
            }
            {
                const int fi = f + 1; const int c = fi / NPIX; const int pp = fi - c * NPIX;
                o.y = __half2float(obuf[pp * OPITCH + c]);
            }
            {
                const int fi = f + 2; const int c = fi / NPIX; const int pp = fi - c * NPIX;
                o.z = __half2float(obuf[pp * OPITCH + c]);
            }
            {
                const int fi = f + 3; const int c = fi / NPIX; const int pp = fi - c * NPIX;
                o.w = __half2float(obuf[pp * OPITCH + c]);
            }
            __builtin_nontemporal_store(o, (f32x4*)(op + f));
        }
        __syncthreads();  // protect obuf/soff/swgt before next j overwrites
    }
}

// ---------------- fallback: direct NCHW f32, one thread per output element ----------------
__global__ __launch_bounds__(256) void roi_align_naive(const float* __restrict__ feat,
                                                       const float* __restrict__ rois,
                                                       float* __restrict__ out) {
    const size_t idx = (size_t)blockIdx.x * 256 + threadIdx.x;
    const size_t total = (size_t)KROIS * CCH * NPIX;
    if (idx >= total) return;
    const int pix = (int)(idx % NPIX);
    const int t1  = (int)(idx / NPIX);
    const int c   = t1 % CCH;
    const int k   = t1 / CCH;
    const int ph = pix / 7;
    const int pw = pix - ph * 7;

    const float* r = rois + k * 5;
    const int b = (int)r[0];
    const float x1 = __fsub_rn(__fmul_rn(r[1], SCALE), 0.5f);
    const float y1 = __fsub_rn(__fmul_rn(r[2], SCALE), 0.5f);
    const float x2 = __fsub_rn(__fmul_rn(r[3], SCALE), 0.5f);
    const float y2 = __fsub_rn(__fmul_rn(r[4], SCALE), 0.5f);
    const float bw = __fdiv_rn(__fsub_rn(x2, x1), (float)OUTW);
    const float bh = __fdiv_rn(__fsub_rn(y2, y1), (float)OUTH);
    const float* fp = feat + (size_t)(b * CCH + c) * FHW;

    float acc = 0.f;
#pragma unroll
    for (int s = 0; s < 4; ++s) {
        const int sy = s >> 1, sx = s & 1;
        const float fy = (float)ph + (sy ? 0.75f : 0.25f);
        const float fx = (float)pw + (sx ? 0.75f : 0.25f);
        const float y = __fadd_rn(y1, __fmul_rn(fy, bh));
        const float x = __fadd_rn(x1, __fmul_rn(fx, bw));
        if (y > -1.0f && y < (float)FH && x > -1.0f && x < (float)FW) {
            const float yc = fmaxf(y, 0.0f);
            const float xc = fmaxf(x, 0.0f);
            int y0 = (int)yc; if (y0 > FH - 1) y0 = FH - 1;
            int x0 = (int)xc; if (x0 > FW - 1) x0 = FW - 1;
            const int y1i = min(y0 + 1, FH - 1);
            const int x1i = min(x0 + 1, FW - 1);
            const float ly = fminf(yc - (float)y0, 1.0f);
            const float lx = fminf(xc - (float)x0, 1.0f);
            const float hy = 1.0f - ly, hx = 1.0f - lx;
            acc += (hy * hx) * fp[y0  * FW + x0 ] + (hy * lx) * fp[y0  * FW + x1i]
                 + (ly * hx) * fp[y1i * FW + x0 ] + (ly * lx) * fp[y1i * FW + x1i];
        }
    }
    out[idx] = acc * 0.25f;
}

extern "C" void kernel_launch(void* const* d_in, const int* in_sizes, int n_in,
                              void* d_out, int out_size, void* d_ws, size_t ws_size,
                              hipStream_t stream) {
    const float* feat = (const float*)d_in[0];
    const float* rois = (const float*)d_in[1];
    float* out = (float*)d_out;

    const size_t nhwc_bytes = (size_t)NIMG * CCH * FHW * sizeof(__half);  // 16.8 MB
    const size_t need = nhwc_bytes + KROIS * sizeof(int) + 32;
    if (ws_size >= need) {
        __half* nhwc = (__half*)d_ws;
        int* perm = (int*)((char*)d_ws + nhwc_bytes);
        int* bases = perm + KROIS;
        prep_fused<<<dim3(8193), dim3(256), 0, stream>>>(feat, nhwc, rois, perm, bases);
        roi_align_nhwc<<<dim3(8 * MAXJ), dim3(256), 0, stream>>>(nhwc, rois, perm, bases, out);
    } else {
        const size_t total = (size_t)KROIS * CCH * NPIX;
        roi_align_naive<<<dim3((unsigned)((total + 255) / 256)), dim3(256), 0, stream>>>(feat, rois, out);
    }
}